// Round 7
// baseline (17826.265 us; speedup 1.0000x reference)
//
#include <hip/hip_runtime.h>

typedef unsigned short ushort_t;
typedef unsigned int uint_t;

// Problem dims: B=32 N=256 T=13 CIN=2 HID=64 EMB=10 K=2
// Output: float32 (B,N,13,HID)
// ws byte layout (total 7,202,816 B ~ 6.9 MB):
//   [0,       2048)      per-batch barrier counters (32 slots x 64B)
//   [2048,    526336)    canonical fp32 inputs (weights+biases+x0)
//   [526336,  583680)    BW: bf16 copies of the 5 big matmul weights
//   [583680,  845824)    A    fp32 256x256
//   [845824,  911360)    bn   fp32 256x64
//   [911360,  5105664)   Wn   bf16 256x2x64x64
//   [5105664, 7202816)   XB   bf16 2 x (8192x64) x-exchange double buffer
#define BAR_OFF 0
#define CW_OFF  2048
#define BW_OFF  526336
#define A_OFF   583680
#define BN_OFF  845824
#define WN_OFF  911360
#define XB_OFF  5105664

// float-element offsets inside canonical region F
#define F_X0     0
#define F_WH     16384
#define F_BH     16512
#define F_WZ     16576
#define F_BZ     16704
#define F_WFIN   16768
#define F_BFIN   20864
#define F_WFHID  20928
#define F_BFHID  25024
#define F_WFOUT  25088
#define F_BFOUT  33280
#define F_WGIN   33408
#define F_BGIN   37504
#define F_WGOUT  37568
#define F_BGOUT  45760
#define F_EG     45888
#define F_WPOOL  48448
#define F_BPOOL  130368

// ushort-element offsets inside BW region (bf16 weights)
#define BW_WFIN  0
#define BW_WFHID 4096
#define BW_WFOUT 8192
#define BW_WGIN  16384
#define BW_WGOUT 20480

__device__ __forceinline__ float bfl(uint_t u){ union{uint_t i; float f;} c; c.i = u<<16; return c.f; }
__device__ __forceinline__ float bfh(uint_t u){ union{uint_t i; float f;} c; c.i = u & 0xffff0000u; return c.f; }
__device__ __forceinline__ float bf1(ushort_t u){ union{uint_t i; float f;} c; c.i = ((uint_t)u)<<16; return c.f; }
__device__ __forceinline__ uint_t f2bf(float x){
  uint_t u = __float_as_uint(x);
  uint_t r = u + 0x7fffu + ((u >> 16) & 1u);
  return r >> 16;
}
__device__ __forceinline__ float fast_tanh(float x){
  float e = __expf(2.0f*x);
  return 1.0f - 2.0f/(e+1.0f);
}
// input dtype probe: times = arange(T). bf16 -> word0 = 0x3F800000; f32 -> 0x00000000
__device__ __forceinline__ bool inputs_are_f32(const void* times){
  return ((const uint_t*)times)[0] != 0x3F800000u;
}

// acc[0..3] += sum_i act[i] * W[i*64 + o0 + j]   (W bf16, row stride 64)
__device__ __forceinline__ void dot64_4(const float* act, const ushort_t* W, int o0, float acc[4]) {
  const float4* a4 = (const float4*)act;
  #pragma unroll
  for (int i4 = 0; i4 < 16; ++i4) {
    float4 av4 = a4[i4];
    float av[4] = {av4.x, av4.y, av4.z, av4.w};
    const ushort_t* wp = W + i4*4*64 + o0;
    #pragma unroll
    for (int ii = 0; ii < 4; ++ii) {
      uint2 w = *(const uint2*)(wp + ii*64);
      acc[0] += av[ii]*bfl(w.x);
      acc[1] += av[ii]*bfh(w.x);
      acc[2] += av[ii]*bfl(w.y);
      acc[3] += av[ii]*bfh(w.y);
    }
  }
}

// acc[0..7] += sum_i act[i] * W[i*128 + co0 + j]  (W bf16, row stride 128)
__device__ __forceinline__ void dot64_8(const float* act, const ushort_t* W, int co0, float acc[8]) {
  const float4* a4 = (const float4*)act;
  #pragma unroll
  for (int i4 = 0; i4 < 16; ++i4) {
    float4 av4 = a4[i4];
    float av[4] = {av4.x, av4.y, av4.z, av4.w};
    const ushort_t* wp = W + i4*4*128 + co0;
    #pragma unroll
    for (int ii = 0; ii < 4; ++ii) {
      uint4 w = *(const uint4*)(wp + ii*128);
      float a = av[ii];
      acc[0] += a*bfl(w.x); acc[1] += a*bfh(w.x);
      acc[2] += a*bfl(w.y); acc[3] += a*bfh(w.y);
      acc[4] += a*bfl(w.z); acc[5] += a*bfh(w.z);
      acc[6] += a*bfl(w.w); acc[7] += a*bfh(w.w);
    }
  }
}

// per-batch 8-block barrier: monotone counter, agent scope (validated: r3 == r4 bit-identical)
__device__ __forceinline__ void batch_sync(uint_t* cnt, int gen) {
  __syncthreads();
  __threadfence();
  if (threadIdx.x == 0) {
    __hip_atomic_fetch_add(cnt, 1u, __ATOMIC_ACQ_REL, __HIP_MEMORY_SCOPE_AGENT);
    while (__hip_atomic_load(cnt, __ATOMIC_ACQUIRE, __HIP_MEMORY_SCOPE_AGENT) < (uint_t)(8*gen)) {}
  }
  __syncthreads();
  __threadfence();
}

// canonicalize weights + x0 slice to fp32 in ws; bf16 copies of the 5 big weights
__global__ __launch_bounds__(256) void k_conv(
    const void* times, const void* ca,
    const void* W_h, const void* b_h, const void* W_z, const void* b_z,
    const void* Wf_in, const void* bf_in, const void* Wf_hid, const void* bf_hid,
    const void* Wf_out, const void* bf_out, const void* Wg_in, const void* bg_in,
    const void* Wg_out, const void* bg_out, const void* Eg, const void* W_pool,
    const void* b_pool, char* __restrict__ wsb)
{
  const bool f32in = inputs_are_f32(times);
  float* F = (float*)(wsb + CW_OFF);
  ushort_t* BW = (ushort_t*)(wsb + BW_OFF);
  if (blockIdx.x == 0) {
    for (int i = threadIdx.x; i < 16384; i += 256) {
      int si = (i >> 1)*24 + (i & 1);
      F[F_X0 + i] = f32in ? ((const float*)ca)[si] : bf1(((const ushort_t*)ca)[si]);
    }
    return;
  }
  const void* src = nullptr; int dst = 0, cnt = 0, bdst = -1;
  switch (blockIdx.x) {
    case 1:  src = W_h;    dst = F_WH;    cnt = 128;   break;
    case 2:  src = b_h;    dst = F_BH;    cnt = 64;    break;
    case 3:  src = W_z;    dst = F_WZ;    cnt = 128;   break;
    case 4:  src = b_z;    dst = F_BZ;    cnt = 64;    break;
    case 5:  src = Wf_in;  dst = F_WFIN;  cnt = 4096;  bdst = BW_WFIN;  break;
    case 6:  src = bf_in;  dst = F_BFIN;  cnt = 64;    break;
    case 7:  src = Wf_hid; dst = F_WFHID; cnt = 4096;  bdst = BW_WFHID; break;
    case 8:  src = bf_hid; dst = F_BFHID; cnt = 64;    break;
    case 9:  src = Wf_out; dst = F_WFOUT; cnt = 8192;  bdst = BW_WFOUT; break;
    case 10: src = bf_out; dst = F_BFOUT; cnt = 128;   break;
    case 11: src = Wg_in;  dst = F_WGIN;  cnt = 4096;  bdst = BW_WGIN;  break;
    case 12: src = bg_in;  dst = F_BGIN;  cnt = 64;    break;
    case 13: src = Wg_out; dst = F_WGOUT; cnt = 8192;  bdst = BW_WGOUT; break;
    case 14: src = bg_out; dst = F_BGOUT; cnt = 128;   break;
    case 15: src = Eg;     dst = F_EG;    cnt = 2560;  break;
    case 16: src = W_pool; dst = F_WPOOL; cnt = 81920; break;
    default: src = b_pool; dst = F_BPOOL; cnt = 640;   break;
  }
  for (int i = threadIdx.x; i < cnt; i += 256) {
    float v = f32in ? ((const float*)src)[i] : bf1(((const ushort_t*)src)[i]);
    F[dst + i] = v;
    if (bdst >= 0) BW[bdst + i] = (ushort_t)f2bf(v);
  }
}

// A = softmax(relu(Eg @ Eg^T), axis=1) ; bn = Eg @ b_pool ; zero barrier slots
__global__ __launch_bounds__(256) void k_A(char* __restrict__ wsb) {
  uint_t* bar = (uint_t*)(wsb + BAR_OFF);
  const float* F = (const float*)(wsb + CW_OFF);
  float* Aw = (float*)(wsb + A_OFF);
  float* bn = (float*)(wsb + BN_OFF);
  const int nrow = blockIdx.x;
  const int m = threadIdx.x;
  if (nrow == 0 && m < 32) bar[m*16] = 0u;
  float eg_n[10];
  #pragma unroll
  for (int d = 0; d < 10; ++d) eg_n[d] = F[F_EG + nrow*10 + d];
  float dot = 0.f;
  #pragma unroll
  for (int d = 0; d < 10; ++d) dot += eg_n[d] * F[F_EG + m*10 + d];
  float v = fmaxf(dot, 0.f);
  __shared__ float red[256];
  red[m] = v; __syncthreads();
  for (int off = 128; off > 0; off >>= 1) {
    if (m < off) red[m] = fmaxf(red[m], red[m+off]);
    __syncthreads();
  }
  float vmax = red[0]; __syncthreads();
  float e = __expf(v - vmax);
  red[m] = e; __syncthreads();
  for (int off = 128; off > 0; off >>= 1) {
    if (m < off) red[m] += red[m+off];
    __syncthreads();
  }
  float ssum = red[0];
  Aw[nrow*256 + m] = e / ssum;
  if (m < 64) {
    float acc = 0.f;
    #pragma unroll
    for (int d = 0; d < 10; ++d) acc += eg_n[d] * F[F_BPOOL + d*64 + m];
    bn[nrow*64 + m] = acc;
  }
}

// Wn[n][k][i][o] = sum_d Eg[n,d] * W_pool[d,k,i,o]   (stored bf16)
__global__ __launch_bounds__(256) void k_Wn(char* __restrict__ wsb) {
  const float* F = (const float*)(wsb + CW_OFF);
  ushort_t* Wn = (ushort_t*)(wsb + WN_OFF);
  int idx = blockIdx.x*256 + threadIdx.x;   // < 2097152
  int o = idx & 63;
  int i = (idx >> 6) & 63;
  int k = (idx >> 12) & 1;
  int n = idx >> 13;
  float acc = 0.f;
  #pragma unroll
  for (int d = 0; d < 10; ++d)
    acc += F[F_EG + n*10 + d] * F[F_WPOOL + ((d*2 + k)*64 + i)*64 + o];
  Wn[idx] = (ushort_t)f2bf(acc);
}

// fused persistent kernel: all 48 RK stages, state in registers,
// per-batch 8-block barrier for the x-exchange (structure validated in r3/r4)
__global__ __launch_bounds__(512) void k_main(
    const void* __restrict__ times,
    const void* __restrict__ cbv, const void* __restrict__ ccv, const void* __restrict__ cdv,
    char* __restrict__ wsb, float* __restrict__ out)
{
  uint_t* bar = (uint_t*)(wsb + BAR_OFF);
  const float* F  = (const float*)(wsb + CW_OFF);
  const ushort_t* BW = (const ushort_t*)(wsb + BW_OFF);
  const float* Aw = (const float*)(wsb + A_OFF);
  const float* bn = (const float*)(wsb + BN_OFF);
  const ushort_t* Wn = (const ushort_t*)(wsb + WN_OFF);
  ushort_t* XB = (ushort_t*)(wsb + XB_OFF);
  const bool f32in = inputs_are_f32(times);

  const int tid = threadIdx.x;
  const int lr  = tid >> 4;        // local row 0..31
  const int t16 = tid & 15;
  const int o0  = t16 * 4;         // 4 output channels per thread
  const int co0 = o0 * 2;          // 8 cols in the 128-wide matmuls
  const int bb  = blockIdx.x >> 3; // batch
  const int nr  = blockIdx.x & 7;  // node-slice
  const int n   = nr * 32 + lr;
  const int row = bb * 256 + n;
  uint_t* cnt = bar + bb*16;

  __shared__ __align__(16) float sIn[32][68];
  __shared__ __align__(16) float sT [32][68];
  __shared__ __align__(16) float sX [32][68];
  __shared__ __align__(16) float xs [128][68];   // 60928 B static LDS

  // h0 = x0@W_h + b_h ; z0 = x0@W_z + b_z ; out[:, :, 0, :] = z0 (fp32)
  float h[4], z[4];
  {
    float a0 = F[F_X0 + row*2 + 0];
    float a1 = F[F_X0 + row*2 + 1];
    #pragma unroll
    for (int j = 0; j < 4; ++j) {
      h[j] = a0*F[F_WH + o0+j] + a1*F[F_WH + 64+o0+j] + F[F_BH + o0+j];
      z[j] = a0*F[F_WZ + o0+j] + a1*F[F_WZ + 64+o0+j] + F[F_BZ + o0+j];
    }
    *(float4*)(out + (row*13)*64 + o0) = make_float4(z[0],z[1],z[2],z[3]);
  }

  float k1h[4],k1z[4],k2h[4],k2z[4],uh[4],uz[4];
  int gen = 0;

  #pragma unroll 1
  for (int s = 0; s < 12; ++s) {
    #pragma unroll
    for (int j=0;j<4;++j){ uh[j]=h[j]; uz[j]=z[j]; }
    #pragma unroll 1
    for (int st = 0; st < 4; ++st) {
      const int vfc = s*4 + st;
      ushort_t* Xc = XB + (vfc & 1) * 524288;

      __syncthreads();                          // protect previous stage's LDS reads
      *(float4*)&sIn[lr][o0] = make_float4(uz[0],uz[1],uz[2],uz[3]);
      __syncthreads();

      // x = relu(uz @ Wg_in + bg_in); publish to exchange buffer (bf16)
      float xr[4];
      { float4 bv = *(const float4*)(F + F_BGIN + o0);
        xr[0]=bv.x; xr[1]=bv.y; xr[2]=bv.z; xr[3]=bv.w; }
      dot64_4(&sIn[lr][0], BW + BW_WGIN, o0, xr);
      #pragma unroll
      for (int j=0;j<4;++j) xr[j] = fmaxf(xr[j], 0.f);
      *(float4*)&sX[lr][o0] = make_float4(xr[0],xr[1],xr[2],xr[3]);
      { uint2 pk;
        pk.x = f2bf(xr[0]) | (f2bf(xr[1]) << 16);
        pk.y = f2bf(xr[2]) | (f2bf(xr[3]) << 16);
        *(uint2*)(Xc + row*64 + o0) = pk; }
      __syncthreads();

      // f-path (row-local): a1 = relu(uh@Wf_in+b); a2 = relu(a1@Wf_hid+b); f = tanh(a2@Wf_out+b)
      *(float4*)&sIn[lr][o0] = make_float4(uh[0],uh[1],uh[2],uh[3]);
      __syncthreads();
      float a1v[4];
      { float4 bv = *(const float4*)(F + F_BFIN + o0);
        a1v[0]=bv.x; a1v[1]=bv.y; a1v[2]=bv.z; a1v[3]=bv.w; }
      dot64_4(&sIn[lr][0], BW + BW_WFIN, o0, a1v);
      #pragma unroll
      for (int j=0;j<4;++j) a1v[j] = fmaxf(a1v[j], 0.f);
      *(float4*)&sT[lr][o0] = make_float4(a1v[0],a1v[1],a1v[2],a1v[3]);
      __syncthreads();
      float a2v[4];
      { float4 bv = *(const float4*)(F + F_BFHID + o0);
        a2v[0]=bv.x; a2v[1]=bv.y; a2v[2]=bv.z; a2v[3]=bv.w; }
      dot64_4(&sT[lr][0], BW + BW_WFHID, o0, a2v);
      #pragma unroll
      for (int j=0;j<4;++j) a2v[j] = fmaxf(a2v[j], 0.f);
      *(float4*)&sIn[lr][o0] = make_float4(a2v[0],a2v[1],a2v[2],a2v[3]);
      __syncthreads();
      float fo[8];
      { float4 b0 = *(const float4*)(F + F_BFOUT + co0);
        float4 b1 = *(const float4*)(F + F_BFOUT + co0 + 4);
        fo[0]=b0.x; fo[1]=b0.y; fo[2]=b0.z; fo[3]=b0.w;
        fo[4]=b1.x; fo[5]=b1.y; fo[6]=b1.z; fo[7]=b1.w; }
      dot64_8(&sIn[lr][0], BW + BW_WFOUT, co0, fo);
      float f0[4], f1[4];
      #pragma unroll
      for (int j=0;j<4;++j){ f0[j]=fast_tanh(fo[2*j]); f1[j]=fast_tanh(fo[2*j+1]); }

      // cross-block exchange within this batch
      ++gen;
      batch_sync(cnt, gen);

      // graph conv: y[n] = A[n,:] @ x[b,:,:]   (two 128-row halves through LDS)
      float y[4] = {0.f,0.f,0.f,0.f};
      const float* Arow = Aw + n*256;
      #pragma unroll 1
      for (int half = 0; half < 2; ++half) {
        #pragma unroll
        for (int q = tid; q < 2048; q += 512) {
          int r = q >> 4, c4 = q & 15;
          uint2 w = *(const uint2*)(Xc + (bb*256 + half*128 + r)*64 + c4*4);
          *(float4*)&xs[r][c4*4] = make_float4(bfl(w.x), bfh(w.x), bfl(w.y), bfh(w.y));
        }
        __syncthreads();
        #pragma unroll 4
        for (int m4 = 0; m4 < 32; ++m4) {
          float4 av = *(const float4*)(Arow + half*128 + m4*4);
          float am[4] = {av.x, av.y, av.z, av.w};
          #pragma unroll
          for (int mm = 0; mm < 4; ++mm) {
            float4 xv = *(const float4*)&xs[m4*4+mm][o0];
            y[0] += am[mm]*xv.x; y[1] += am[mm]*xv.y;
            y[2] += am[mm]*xv.z; y[3] += am[mm]*xv.w;
          }
        }
        __syncthreads();
      }

      // og = bn[n] + x@Wn[n,0] + y@Wn[n,1]   (Wn bf16, L2-resident)
      *(float4*)&sT[lr][o0] = make_float4(y[0],y[1],y[2],y[3]);
      __syncthreads();
      float og[4];
      { float4 bv = *(const float4*)(bn + n*64 + o0); og[0]=bv.x; og[1]=bv.y; og[2]=bv.z; og[3]=bv.w; }
      const ushort_t* W0 = Wn + n*8192;
      #pragma unroll
      for (int i4 = 0; i4 < 16; ++i4) {
        float4 xa = *(const float4*)&sX[lr][i4*4];
        float4 ya = *(const float4*)&sT[lr][i4*4];
        float xav[4]={xa.x,xa.y,xa.z,xa.w};
        float yav[4]={ya.x,ya.y,ya.z,ya.w};
        #pragma unroll
        for (int ii = 0; ii < 4; ++ii) {
          int i = i4*4 + ii;
          uint2 w0 = *(const uint2*)(W0 + i*64 + o0);
          uint2 w1 = *(const uint2*)(W0 + 4096 + i*64 + o0);
          og[0] += xav[ii]*bfl(w0.x) + yav[ii]*bfl(w1.x);
          og[1] += xav[ii]*bfh(w0.x) + yav[ii]*bfh(w1.x);
          og[2] += xav[ii]*bfl(w0.y) + yav[ii]*bfl(w1.y);
          og[3] += xav[ii]*bfh(w0.y) + yav[ii]*bfh(w1.y);
        }
      }
      *(float4*)&sIn[lr][o0] = make_float4(og[0],og[1],og[2],og[3]);
      __syncthreads();
      float go[8];
      { float4 b0 = *(const float4*)(F + F_BGOUT + co0);
        float4 b1 = *(const float4*)(F + F_BGOUT + co0 + 4);
        go[0]=b0.x; go[1]=b0.y; go[2]=b0.z; go[3]=b0.w;
        go[4]=b1.x; go[5]=b1.y; go[6]=b1.z; go[7]=b1.w; }
      dot64_8(&sIn[lr][0], BW + BW_WGOUT, co0, go);
      float g0[4], g1[4];
      #pragma unroll
      for (int j=0;j<4;++j){ g0[j]=fast_tanh(go[2*j]); g1[j]=fast_tanh(go[2*j+1]); }

      // dX at this stage's time
      int sidx; float frac;
      if (st == 0)      { sidx = s; frac = 0.f; }
      else if (st == 1) { sidx = s; frac = 0.33333334f; }
      else if (st == 2) { sidx = s; frac = 0.66666669f; }
      else              { sidx = (s < 11) ? s+1 : 11; frac = (s < 11) ? 0.f : 1.f; }
      float dX0, dX1;
      if (f32in) {
        float2 vb = *(const float2*)((const float*)cbv + (row*12 + sidx)*2);
        float2 vc = *(const float2*)((const float*)ccv + (row*12 + sidx)*2);
        float2 vd = *(const float2*)((const float*)cdv + (row*12 + sidx)*2);
        dX0 = vb.x + (vc.x + vd.x*frac)*frac;
        dX1 = vb.y + (vc.y + vd.y*frac)*frac;
      } else {
        uint_t vb = *(const uint_t*)((const ushort_t*)cbv + (row*12 + sidx)*2);
        uint_t vc = *(const uint_t*)((const ushort_t*)ccv + (row*12 + sidx)*2);
        uint_t vd = *(const uint_t*)((const ushort_t*)cdv + (row*12 + sidx)*2);
        dX0 = bfl(vb) + (bfl(vc) + bfl(vd)*frac)*frac;
        dX1 = bfh(vb) + (bfh(vc) + bfh(vd)*frac)*frac;
      }

      float dh[4], dz[4];
      #pragma unroll
      for (int j=0;j<4;++j){
        dh[j] = f0[j]*dX0 + f1[j]*dX1;
        dz[j] = g0[j]*f0[j]*dX0 + g1[j]*f1[j]*dX1;
      }

      if (st == 0) {
        #pragma unroll
        for (int j=0;j<4;++j){
          k1h[j]=dh[j]; k1z[j]=dz[j];
          uh[j]=h[j]+dh[j]*(1.f/3.f); uz[j]=z[j]+dz[j]*(1.f/3.f);
        }
      } else if (st == 1) {
        #pragma unroll
        for (int j=0;j<4;++j){
          k2h[j]=dh[j]; k2z[j]=dz[j];
          uh[j]=h[j]+dh[j]-k1h[j]*(1.f/3.f); uz[j]=z[j]+dz[j]-k1z[j]*(1.f/3.f);
        }
      } else if (st == 2) {
        #pragma unroll
        for (int j=0;j<4;++j){
          uh[j]=h[j]+k1h[j]-k2h[j]+dh[j];  uz[j]=z[j]+k1z[j]-k2z[j]+dz[j];
          k1h[j]=k1h[j]+3.f*(k2h[j]+dh[j]); k1z[j]=k1z[j]+3.f*(k2z[j]+dz[j]);
        }
      } else {
        #pragma unroll
        for (int j=0;j<4;++j){
          h[j] += 0.125f*(k1h[j]+dh[j]);
          z[j] += 0.125f*(k1z[j]+dz[j]);
        }
        *(float4*)(out + (row*13 + s + 1)*64 + o0) = make_float4(z[0],z[1],z[2],z[3]);
      }
    }
  }
}

extern "C" void kernel_launch(void* const* d_in, const int* in_sizes, int n_in,
                              void* d_out, int out_size, void* d_ws, size_t ws_size,
                              hipStream_t stream) {
  const void* times   = d_in[0];
  const void* coeff_a = d_in[1];
  const void* coeff_b = d_in[2];
  const void* coeff_c = d_in[3];
  const void* coeff_d = d_in[4];
  const void* W_h    = d_in[5];
  const void* b_h    = d_in[6];
  const void* W_z    = d_in[7];
  const void* b_z    = d_in[8];
  const void* Wf_in  = d_in[9];
  const void* bf_in  = d_in[10];
  const void* Wf_hid = d_in[11];
  const void* bf_hid = d_in[12];
  const void* Wf_out = d_in[13];
  const void* bf_out = d_in[14];
  const void* Wg_in  = d_in[15];
  const void* bg_in  = d_in[16];
  const void* Eg     = d_in[17];
  const void* W_pool = d_in[18];
  const void* b_pool = d_in[19];
  const void* Wg_out = d_in[20];
  const void* bg_out = d_in[21];

  char* wsb = (char*)d_ws;
  float* out = (float*)d_out;

  hipLaunchKernelGGL(k_conv, dim3(18), dim3(256), 0, stream,
                     times, coeff_a, W_h, b_h, W_z, b_z,
                     Wf_in, bf_in, Wf_hid, bf_hid, Wf_out, bf_out,
                     Wg_in, bg_in, Wg_out, bg_out, Eg, W_pool, b_pool, wsb);
  hipLaunchKernelGGL(k_A,  dim3(256),  dim3(256), 0, stream, wsb);
  hipLaunchKernelGGL(k_Wn, dim3(8192), dim3(256), 0, stream, wsb);
  hipLaunchKernelGGL(k_main, dim3(256), dim3(512), 0, stream,
                     times, coeff_b, coeff_c, coeff_d, wsb, out);
}

// Round 8
// 11176.308 us; speedup vs baseline: 1.5950x; 1.5950x over previous
//
#include <hip/hip_runtime.h>

typedef unsigned short ushort_t;
typedef unsigned int uint_t;

// Problem dims: B=32 N=256 T=13 CIN=2 HID=64 EMB=10 K=2
// Output: float32 (B,N,13,HID)
// ws byte layout (total 7,202,816 B ~ 6.9 MB):
//   [0,       2048)      per-batch barrier counters (32 slots x 64B)
//   [2048,    526336)    canonical fp32 inputs (weights+biases+x0)
//   [526336,  583680)    BW: bf16 copies of the 5 big matmul weights
//   [583680,  845824)    A    fp32 256x256
//   [845824,  911360)    bn   fp32 256x64
//   [911360,  5105664)   Wn   bf16 256x2x64x64
//   [5105664, 7202816)   XB   bf16 2 x (8192x64) x-exchange double buffer
//                        (accessed ONLY via relaxed agent-scope atomics)
#define BAR_OFF 0
#define CW_OFF  2048
#define BW_OFF  526336
#define A_OFF   583680
#define BN_OFF  845824
#define WN_OFF  911360
#define XB_OFF  5105664

// float-element offsets inside canonical region F
#define F_X0     0
#define F_WH     16384
#define F_BH     16512
#define F_WZ     16576
#define F_BZ     16704
#define F_WFIN   16768
#define F_BFIN   20864
#define F_WFHID  20928
#define F_BFHID  25024
#define F_WFOUT  25088
#define F_BFOUT  33280
#define F_WGIN   33408
#define F_BGIN   37504
#define F_WGOUT  37568
#define F_BGOUT  45760
#define F_EG     45888
#define F_WPOOL  48448
#define F_BPOOL  130368

// ushort-element offsets inside BW region (bf16 weights)
#define BW_WFIN  0
#define BW_WFHID 4096
#define BW_WFOUT 8192
#define BW_WGIN  16384
#define BW_WGOUT 20480

__device__ __forceinline__ float bfl(uint_t u){ union{uint_t i; float f;} c; c.i = u<<16; return c.f; }
__device__ __forceinline__ float bfh(uint_t u){ union{uint_t i; float f;} c; c.i = u & 0xffff0000u; return c.f; }
__device__ __forceinline__ float bf1(ushort_t u){ union{uint_t i; float f;} c; c.i = ((uint_t)u)<<16; return c.f; }
__device__ __forceinline__ uint_t f2bf(float x){
  uint_t u = __float_as_uint(x);
  uint_t r = u + 0x7fffu + ((u >> 16) & 1u);
  return r >> 16;
}
__device__ __forceinline__ float fast_tanh(float x){
  float e = __expf(2.0f*x);
  return 1.0f - 2.0f/(e+1.0f);
}
// input dtype probe: times = arange(T). bf16 -> word0 = 0x3F800000; f32 -> 0x00000000
__device__ __forceinline__ bool inputs_are_f32(const void* times){
  return ((const uint_t*)times)[0] != 0x3F800000u;
}

// coherence-point (cross-XCD safe) 32-bit accesses for the x-exchange buffer.
// Relaxed agent-scope atomics emit sc0/sc1 ops on gfx940+: bypass L1/L2,
// no cache-maintenance instructions -> the rest of L2 stays hot.
__device__ __forceinline__ void x_store(uint_t* p, uint_t v){
  __hip_atomic_store(p, v, __ATOMIC_RELAXED, __HIP_MEMORY_SCOPE_AGENT);
}
__device__ __forceinline__ uint_t x_load(const uint_t* p){
  return __hip_atomic_load(p, __ATOMIC_RELAXED, __HIP_MEMORY_SCOPE_AGENT);
}

// per-batch 8-block barrier. RELEASE add orders our write-through x-stores;
// RELAXED poll; NO acquire / NO threadfence anywhere -> no L2 invalidation.
__device__ __forceinline__ void batch_sync(uint_t* cnt, int gen) {
  __syncthreads();
  if (threadIdx.x == 0) {
    __hip_atomic_fetch_add(cnt, 1u, __ATOMIC_RELEASE, __HIP_MEMORY_SCOPE_AGENT);
    while (__hip_atomic_load(cnt, __ATOMIC_RELAXED, __HIP_MEMORY_SCOPE_AGENT) < (uint_t)(8*gen)) {
      __builtin_amdgcn_s_sleep(1);
    }
  }
  __syncthreads();
}

// canonicalize weights + x0 slice to fp32 in ws; bf16 copies of the 5 big weights
__global__ __launch_bounds__(256) void k_conv(
    const void* times, const void* ca,
    const void* W_h, const void* b_h, const void* W_z, const void* b_z,
    const void* Wf_in, const void* bf_in, const void* Wf_hid, const void* bf_hid,
    const void* Wf_out, const void* bf_out, const void* Wg_in, const void* bg_in,
    const void* Wg_out, const void* bg_out, const void* Eg, const void* W_pool,
    const void* b_pool, char* __restrict__ wsb)
{
  const bool f32in = inputs_are_f32(times);
  float* F = (float*)(wsb + CW_OFF);
  ushort_t* BW = (ushort_t*)(wsb + BW_OFF);
  if (blockIdx.x == 0) {
    for (int i = threadIdx.x; i < 16384; i += 256) {
      int si = (i >> 1)*24 + (i & 1);
      F[F_X0 + i] = f32in ? ((const float*)ca)[si] : bf1(((const ushort_t*)ca)[si]);
    }
    return;
  }
  const void* src = nullptr; int dst = 0, cnt = 0, bdst = -1;
  switch (blockIdx.x) {
    case 1:  src = W_h;    dst = F_WH;    cnt = 128;   break;
    case 2:  src = b_h;    dst = F_BH;    cnt = 64;    break;
    case 3:  src = W_z;    dst = F_WZ;    cnt = 128;   break;
    case 4:  src = b_z;    dst = F_BZ;    cnt = 64;    break;
    case 5:  src = Wf_in;  dst = F_WFIN;  cnt = 4096;  bdst = BW_WFIN;  break;
    case 6:  src = bf_in;  dst = F_BFIN;  cnt = 64;    break;
    case 7:  src = Wf_hid; dst = F_WFHID; cnt = 4096;  bdst = BW_WFHID; break;
    case 8:  src = bf_hid; dst = F_BFHID; cnt = 64;    break;
    case 9:  src = Wf_out; dst = F_WFOUT; cnt = 8192;  bdst = BW_WFOUT; break;
    case 10: src = bf_out; dst = F_BFOUT; cnt = 128;   break;
    case 11: src = Wg_in;  dst = F_WGIN;  cnt = 4096;  bdst = BW_WGIN;  break;
    case 12: src = bg_in;  dst = F_BGIN;  cnt = 64;    break;
    case 13: src = Wg_out; dst = F_WGOUT; cnt = 8192;  bdst = BW_WGOUT; break;
    case 14: src = bg_out; dst = F_BGOUT; cnt = 128;   break;
    case 15: src = Eg;     dst = F_EG;    cnt = 2560;  break;
    case 16: src = W_pool; dst = F_WPOOL; cnt = 81920; break;
    default: src = b_pool; dst = F_BPOOL; cnt = 640;   break;
  }
  for (int i = threadIdx.x; i < cnt; i += 256) {
    float v = f32in ? ((const float*)src)[i] : bf1(((const ushort_t*)src)[i]);
    F[dst + i] = v;
    if (bdst >= 0) BW[bdst + i] = (ushort_t)f2bf(v);
  }
}

// A = softmax(relu(Eg @ Eg^T), axis=1) ; bn = Eg @ b_pool ; zero barrier slots
__global__ __launch_bounds__(256) void k_A(char* __restrict__ wsb) {
  uint_t* bar = (uint_t*)(wsb + BAR_OFF);
  const float* F = (const float*)(wsb + CW_OFF);
  float* Aw = (float*)(wsb + A_OFF);
  float* bn = (float*)(wsb + BN_OFF);
  const int nrow = blockIdx.x;
  const int m = threadIdx.x;
  if (nrow == 0 && m < 32)
    __hip_atomic_store(&bar[m*16], 0u, __ATOMIC_RELAXED, __HIP_MEMORY_SCOPE_AGENT);
  float eg_n[10];
  #pragma unroll
  for (int d = 0; d < 10; ++d) eg_n[d] = F[F_EG + nrow*10 + d];
  float dot = 0.f;
  #pragma unroll
  for (int d = 0; d < 10; ++d) dot += eg_n[d] * F[F_EG + m*10 + d];
  float v = fmaxf(dot, 0.f);
  __shared__ float red[256];
  red[m] = v; __syncthreads();
  for (int off = 128; off > 0; off >>= 1) {
    if (m < off) red[m] = fmaxf(red[m], red[m+off]);
    __syncthreads();
  }
  float vmax = red[0]; __syncthreads();
  float e = __expf(v - vmax);
  red[m] = e; __syncthreads();
  for (int off = 128; off > 0; off >>= 1) {
    if (m < off) red[m] += red[m+off];
    __syncthreads();
  }
  float ssum = red[0];
  Aw[nrow*256 + m] = e / ssum;
  if (m < 64) {
    float acc = 0.f;
    #pragma unroll
    for (int d = 0; d < 10; ++d) acc += eg_n[d] * F[F_BPOOL + d*64 + m];
    bn[nrow*64 + m] = acc;
  }
}

// Wn[n][k][i][o] = sum_d Eg[n,d] * W_pool[d,k,i,o]   (stored bf16)
__global__ __launch_bounds__(256) void k_Wn(char* __restrict__ wsb) {
  const float* F = (const float*)(wsb + CW_OFF);
  ushort_t* Wn = (ushort_t*)(wsb + WN_OFF);
  int idx = blockIdx.x*256 + threadIdx.x;   // < 2097152
  int o = idx & 63;
  int i = (idx >> 6) & 63;
  int k = (idx >> 12) & 1;
  int n = idx >> 13;
  float acc = 0.f;
  #pragma unroll
  for (int d = 0; d < 10; ++d)
    acc += F[F_EG + n*10 + d] * F[F_WPOOL + ((d*2 + k)*64 + i)*64 + o];
  Wn[idx] = (ushort_t)f2bf(acc);
}

// fused persistent kernel: all 48 RK stages, state in registers,
// fence-free per-batch barrier + coherence-point x-exchange
__global__ __launch_bounds__(512) void k_main(
    const void* __restrict__ times,
    const void* __restrict__ cbv, const void* __restrict__ ccv, const void* __restrict__ cdv,
    char* __restrict__ wsb, float* __restrict__ out)
{
  uint_t* bar = (uint_t*)(wsb + BAR_OFF);
  const float* F  = (const float*)(wsb + CW_OFF);
  const ushort_t* BW = (const ushort_t*)(wsb + BW_OFF);
  const float* Aw = (const float*)(wsb + A_OFF);
  const float* bn = (const float*)(wsb + BN_OFF);
  const ushort_t* Wn = (const ushort_t*)(wsb + WN_OFF);
  uint_t* XBw = (uint_t*)(wsb + XB_OFF);       // x-exchange as packed bf16x2 words
  const bool f32in = inputs_are_f32(times);

  const int tid = threadIdx.x;
  const int lr  = tid >> 4;        // local row 0..31
  const int t16 = tid & 15;
  const int o0  = t16 * 4;         // 4 output channels per thread
  const int co0 = o0 * 2;          // 8 cols in the 128-wide matmuls
  const int bb  = blockIdx.x >> 3; // batch
  const int nr  = blockIdx.x & 7;  // node-slice (XCD L2 affinity for Wn slice)
  const int n   = nr * 32 + lr;
  const int row = bb * 256 + n;
  uint_t* cnt = bar + bb*16;

  __shared__ __align__(16) float sIn[32][68];
  __shared__ __align__(16) float sT [32][68];
  __shared__ __align__(16) float sX [32][68];
  __shared__ __align__(16) float xs [128][68];   // 60928 B static LDS

  // h0 = x0@W_h + b_h ; z0 = x0@W_z + b_z ; out[:, :, 0, :] = z0 (fp32)
  float h[4], z[4];
  {
    float a0 = F[F_X0 + row*2 + 0];
    float a1 = F[F_X0 + row*2 + 1];
    #pragma unroll
    for (int j = 0; j < 4; ++j) {
      h[j] = a0*F[F_WH + o0+j] + a1*F[F_WH + 64+o0+j] + F[F_BH + o0+j];
      z[j] = a0*F[F_WZ + o0+j] + a1*F[F_WZ + 64+o0+j] + F[F_BZ + o0+j];
    }
    *(float4*)(out + (row*13)*64 + o0) = make_float4(z[0],z[1],z[2],z[3]);
  }

  float k1h[4],k1z[4],k2h[4],k2z[4],uh[4],uz[4];
  int gen = 0;

  #pragma unroll 1
  for (int s = 0; s < 12; ++s) {
    #pragma unroll
    for (int j=0;j<4;++j){ uh[j]=h[j]; uz[j]=z[j]; }
    #pragma unroll 1
    for (int st = 0; st < 4; ++st) {
      const int vfc = s*4 + st;
      uint_t* Xc = XBw + (vfc & 1) * 262144;    // 8192 rows x 32 words

      __syncthreads();                          // protect previous stage's LDS reads
      *(float4*)&sIn[lr][o0] = make_float4(uz[0],uz[1],uz[2],uz[3]);
      __syncthreads();

      // x = relu(uz @ Wg_in + bg_in); publish via coherence-point stores
      float xr[4];
      { float4 bv = *(const float4*)(F + F_BGIN + o0);
        xr[0]=bv.x; xr[1]=bv.y; xr[2]=bv.z; xr[3]=bv.w; }
      { const float4* a4 = (const float4*)&sIn[lr][0];
        const ushort_t* W = BW + BW_WGIN;
        #pragma unroll
        for (int i4 = 0; i4 < 16; ++i4) {
          float4 av4 = a4[i4];
          float av[4] = {av4.x, av4.y, av4.z, av4.w};
          const ushort_t* wp = W + i4*4*64 + o0;
          #pragma unroll
          for (int ii = 0; ii < 4; ++ii) {
            uint2 w = *(const uint2*)(wp + ii*64);
            xr[0] += av[ii]*bfl(w.x); xr[1] += av[ii]*bfh(w.x);
            xr[2] += av[ii]*bfl(w.y); xr[3] += av[ii]*bfh(w.y);
          }
        } }
      #pragma unroll
      for (int j=0;j<4;++j) xr[j] = fmaxf(xr[j], 0.f);
      *(float4*)&sX[lr][o0] = make_float4(xr[0],xr[1],xr[2],xr[3]);
      x_store(Xc + row*32 + t16*2,     f2bf(xr[0]) | (f2bf(xr[1]) << 16));
      x_store(Xc + row*32 + t16*2 + 1, f2bf(xr[2]) | (f2bf(xr[3]) << 16));
      __syncthreads();

      // f-path (row-local): a1 = relu(uh@Wf_in+b); a2 = relu(a1@Wf_hid+b); f = tanh(a2@Wf_out+b)
      *(float4*)&sIn[lr][o0] = make_float4(uh[0],uh[1],uh[2],uh[3]);
      __syncthreads();
      float a1v[4];
      { float4 bv = *(const float4*)(F + F_BFIN + o0);
        a1v[0]=bv.x; a1v[1]=bv.y; a1v[2]=bv.z; a1v[3]=bv.w; }
      { const float4* a4 = (const float4*)&sIn[lr][0];
        const ushort_t* W = BW + BW_WFIN;
        #pragma unroll
        for (int i4 = 0; i4 < 16; ++i4) {
          float4 av4 = a4[i4];
          float av[4] = {av4.x, av4.y, av4.z, av4.w};
          const ushort_t* wp = W + i4*4*64 + o0;
          #pragma unroll
          for (int ii = 0; ii < 4; ++ii) {
            uint2 w = *(const uint2*)(wp + ii*64);
            a1v[0] += av[ii]*bfl(w.x); a1v[1] += av[ii]*bfh(w.x);
            a1v[2] += av[ii]*bfl(w.y); a1v[3] += av[ii]*bfh(w.y);
          }
        } }
      #pragma unroll
      for (int j=0;j<4;++j) a1v[j] = fmaxf(a1v[j], 0.f);
      *(float4*)&sT[lr][o0] = make_float4(a1v[0],a1v[1],a1v[2],a1v[3]);
      __syncthreads();
      float a2v[4];
      { float4 bv = *(const float4*)(F + F_BFHID + o0);
        a2v[0]=bv.x; a2v[1]=bv.y; a2v[2]=bv.z; a2v[3]=bv.w; }
      { const float4* a4 = (const float4*)&sT[lr][0];
        const ushort_t* W = BW + BW_WFHID;
        #pragma unroll
        for (int i4 = 0; i4 < 16; ++i4) {
          float4 av4 = a4[i4];
          float av[4] = {av4.x, av4.y, av4.z, av4.w};
          const ushort_t* wp = W + i4*4*64 + o0;
          #pragma unroll
          for (int ii = 0; ii < 4; ++ii) {
            uint2 w = *(const uint2*)(wp + ii*64);
            a2v[0] += av[ii]*bfl(w.x); a2v[1] += av[ii]*bfh(w.x);
            a2v[2] += av[ii]*bfl(w.y); a2v[3] += av[ii]*bfh(w.y);
          }
        } }
      #pragma unroll
      for (int j=0;j<4;++j) a2v[j] = fmaxf(a2v[j], 0.f);
      *(float4*)&sIn[lr][o0] = make_float4(a2v[0],a2v[1],a2v[2],a2v[3]);
      __syncthreads();
      float fo[8];
      { float4 b0 = *(const float4*)(F + F_BFOUT + co0);
        float4 b1 = *(const float4*)(F + F_BFOUT + co0 + 4);
        fo[0]=b0.x; fo[1]=b0.y; fo[2]=b0.z; fo[3]=b0.w;
        fo[4]=b1.x; fo[5]=b1.y; fo[6]=b1.z; fo[7]=b1.w; }
      { const float4* a4 = (const float4*)&sIn[lr][0];
        const ushort_t* W = BW + BW_WFOUT;
        #pragma unroll
        for (int i4 = 0; i4 < 16; ++i4) {
          float4 av4 = a4[i4];
          float av[4] = {av4.x, av4.y, av4.z, av4.w};
          const ushort_t* wp = W + i4*4*128 + co0;
          #pragma unroll
          for (int ii = 0; ii < 4; ++ii) {
            uint4 w = *(const uint4*)(wp + ii*128);
            float a = av[ii];
            fo[0] += a*bfl(w.x); fo[1] += a*bfh(w.x);
            fo[2] += a*bfl(w.y); fo[3] += a*bfh(w.y);
            fo[4] += a*bfl(w.z); fo[5] += a*bfh(w.z);
            fo[6] += a*bfl(w.w); fo[7] += a*bfh(w.w);
          }
        } }
      float f0[4], f1[4];
      #pragma unroll
      for (int j=0;j<4;++j){ f0[j]=fast_tanh(fo[2*j]); f1[j]=fast_tanh(fo[2*j+1]); }

      // cross-block exchange within this batch (fence-free)
      ++gen;
      batch_sync(cnt, gen);

      // graph conv: y[n] = A[n,:] @ x[b,:,:]   (two 128-row halves through LDS)
      float y[4] = {0.f,0.f,0.f,0.f};
      const float* Arow = Aw + n*256;
      #pragma unroll 1
      for (int half = 0; half < 2; ++half) {
        #pragma unroll
        for (int q = tid; q < 2048; q += 512) {
          int r = q >> 4, c4 = q & 15;
          const uint_t* xp = Xc + (bb*256 + half*128 + r)*32 + c4*2;
          uint_t w0 = x_load(xp);
          uint_t w1 = x_load(xp + 1);
          *(float4*)&xs[r][c4*4] = make_float4(bfl(w0), bfh(w0), bfl(w1), bfh(w1));
        }
        __syncthreads();
        #pragma unroll 4
        for (int m4 = 0; m4 < 32; ++m4) {
          float4 av = *(const float4*)(Arow + half*128 + m4*4);
          float am[4] = {av.x, av.y, av.z, av.w};
          #pragma unroll
          for (int mm = 0; mm < 4; ++mm) {
            float4 xv = *(const float4*)&xs[m4*4+mm][o0];
            y[0] += am[mm]*xv.x; y[1] += am[mm]*xv.y;
            y[2] += am[mm]*xv.z; y[3] += am[mm]*xv.w;
          }
        }
        __syncthreads();
      }

      // og = bn[n] + x@Wn[n,0] + y@Wn[n,1]   (Wn bf16, stays L2-resident now)
      *(float4*)&sT[lr][o0] = make_float4(y[0],y[1],y[2],y[3]);
      __syncthreads();
      float og[4];
      { float4 bv = *(const float4*)(bn + n*64 + o0); og[0]=bv.x; og[1]=bv.y; og[2]=bv.z; og[3]=bv.w; }
      const ushort_t* W0 = Wn + n*8192;
      #pragma unroll
      for (int i4 = 0; i4 < 16; ++i4) {
        float4 xa = *(const float4*)&sX[lr][i4*4];
        float4 ya = *(const float4*)&sT[lr][i4*4];
        float xav[4]={xa.x,xa.y,xa.z,xa.w};
        float yav[4]={ya.x,ya.y,ya.z,ya.w};
        #pragma unroll
        for (int ii = 0; ii < 4; ++ii) {
          int i = i4*4 + ii;
          uint2 w0 = *(const uint2*)(W0 + i*64 + o0);
          uint2 w1 = *(const uint2*)(W0 + 4096 + i*64 + o0);
          og[0] += xav[ii]*bfl(w0.x) + yav[ii]*bfl(w1.x);
          og[1] += xav[ii]*bfh(w0.x) + yav[ii]*bfh(w1.x);
          og[2] += xav[ii]*bfl(w0.y) + yav[ii]*bfl(w1.y);
          og[3] += xav[ii]*bfh(w0.y) + yav[ii]*bfh(w1.y);
        }
      }
      *(float4*)&sIn[lr][o0] = make_float4(og[0],og[1],og[2],og[3]);
      __syncthreads();
      float go[8];
      { float4 b0 = *(const float4*)(F + F_BGOUT + co0);
        float4 b1 = *(const float4*)(F + F_BGOUT + co0 + 4);
        go[0]=b0.x; go[1]=b0.y; go[2]=b0.z; go[3]=b0.w;
        go[4]=b1.x; go[5]=b1.y; go[6]=b1.z; go[7]=b1.w; }
      { const float4* a4 = (const float4*)&sIn[lr][0];
        const ushort_t* W = BW + BW_WGOUT;
        #pragma unroll
        for (int i4 = 0; i4 < 16; ++i4) {
          float4 av4 = a4[i4];
          float av[4] = {av4.x, av4.y, av4.z, av4.w};
          const ushort_t* wp = W + i4*4*128 + co0;
          #pragma unroll
          for (int ii = 0; ii < 4; ++ii) {
            uint4 w = *(const uint4*)(wp + ii*128);
            float a = av[ii];
            go[0] += a*bfl(w.x); go[1] += a*bfh(w.x);
            go[2] += a*bfl(w.y); go[3] += a*bfh(w.y);
            go[4] += a*bfl(w.z); go[5] += a*bfh(w.z);
            go[6] += a*bfl(w.w); go[7] += a*bfh(w.w);
          }
        } }
      float g0[4], g1[4];
      #pragma unroll
      for (int j=0;j<4;++j){ g0[j]=fast_tanh(go[2*j]); g1[j]=fast_tanh(go[2*j+1]); }

      // dX at this stage's time
      int sidx; float frac;
      if (st == 0)      { sidx = s; frac = 0.f; }
      else if (st == 1) { sidx = s; frac = 0.33333334f; }
      else if (st == 2) { sidx = s; frac = 0.66666669f; }
      else              { sidx = (s < 11) ? s+1 : 11; frac = (s < 11) ? 0.f : 1.f; }
      float dX0, dX1;
      if (f32in) {
        float2 vb = *(const float2*)((const float*)cbv + (row*12 + sidx)*2);
        float2 vc = *(const float2*)((const float*)ccv + (row*12 + sidx)*2);
        float2 vd = *(const float2*)((const float*)cdv + (row*12 + sidx)*2);
        dX0 = vb.x + (vc.x + vd.x*frac)*frac;
        dX1 = vb.y + (vc.y + vd.y*frac)*frac;
      } else {
        uint_t vb = *(const uint_t*)((const ushort_t*)cbv + (row*12 + sidx)*2);
        uint_t vc = *(const uint_t*)((const ushort_t*)ccv + (row*12 + sidx)*2);
        uint_t vd = *(const uint_t*)((const ushort_t*)cdv + (row*12 + sidx)*2);
        dX0 = bfl(vb) + (bfl(vc) + bfl(vd)*frac)*frac;
        dX1 = bfh(vb) + (bfh(vc) + bfh(vd)*frac)*frac;
      }

      float dh[4], dz[4];
      #pragma unroll
      for (int j=0;j<4;++j){
        dh[j] = f0[j]*dX0 + f1[j]*dX1;
        dz[j] = g0[j]*f0[j]*dX0 + g1[j]*f1[j]*dX1;
      }

      if (st == 0) {
        #pragma unroll
        for (int j=0;j<4;++j){
          k1h[j]=dh[j]; k1z[j]=dz[j];
          uh[j]=h[j]+dh[j]*(1.f/3.f); uz[j]=z[j]+dz[j]*(1.f/3.f);
        }
      } else if (st == 1) {
        #pragma unroll
        for (int j=0;j<4;++j){
          k2h[j]=dh[j]; k2z[j]=dz[j];
          uh[j]=h[j]+dh[j]-k1h[j]*(1.f/3.f); uz[j]=z[j]+dz[j]-k1z[j]*(1.f/3.f);
        }
      } else if (st == 2) {
        #pragma unroll
        for (int j=0;j<4;++j){
          uh[j]=h[j]+k1h[j]-k2h[j]+dh[j];  uz[j]=z[j]+k1z[j]-k2z[j]+dz[j];
          k1h[j]=k1h[j]+3.f*(k2h[j]+dh[j]); k1z[j]=k1z[j]+3.f*(k2z[j]+dz[j]);
        }
      } else {
        #pragma unroll
        for (int j=0;j<4;++j){
          h[j] += 0.125f*(k1h[j]+dh[j]);
          z[j] += 0.125f*(k1z[j]+dz[j]);
        }
        *(float4*)(out + (row*13 + s + 1)*64 + o0) = make_float4(z[0],z[1],z[2],z[3]);
      }
    }
  }
}

extern "C" void kernel_launch(void* const* d_in, const int* in_sizes, int n_in,
                              void* d_out, int out_size, void* d_ws, size_t ws_size,
                              hipStream_t stream) {
  const void* times   = d_in[0];
  const void* coeff_a = d_in[1];
  const void* coeff_b = d_in[2];
  const void* coeff_c = d_in[3];
  const void* coeff_d = d_in[4];
  const void* W_h    = d_in[5];
  const void* b_h    = d_in[6];
  const void* W_z    = d_in[7];
  const void* b_z    = d_in[8];
  const void* Wf_in  = d_in[9];
  const void* bf_in  = d_in[10];
  const void* Wf_hid = d_in[11];
  const void* bf_hid = d_in[12];
  const void* Wf_out = d_in[13];
  const void* bf_out = d_in[14];
  const void* Wg_in  = d_in[15];
  const void* bg_in  = d_in[16];
  const void* Eg     = d_in[17];
  const void* W_pool = d_in[18];
  const void* b_pool = d_in[19];
  const void* Wg_out = d_in[20];
  const void* bg_out = d_in[21];

  char* wsb = (char*)d_ws;
  float* out = (float*)d_out;

  hipLaunchKernelGGL(k_conv, dim3(18), dim3(256), 0, stream,
                     times, coeff_a, W_h, b_h, W_z, b_z,
                     Wf_in, bf_in, Wf_hid, bf_hid, Wf_out, bf_out,
                     Wg_in, bg_in, Wg_out, bg_out, Eg, W_pool, b_pool, wsb);
  hipLaunchKernelGGL(k_A,  dim3(256),  dim3(256), 0, stream, wsb);
  hipLaunchKernelGGL(k_Wn, dim3(8192), dim3(256), 0, stream, wsb);
  hipLaunchKernelGGL(k_main, dim3(256), dim3(512), 0, stream,
                     times, coeff_b, coeff_c, coeff_d, wsb, out);
}